// Round 2
// baseline (578.008 us; speedup 1.0000x reference)
//
#include <hip/hip_runtime.h>
#include <hip/hip_bf16.h>

typedef float f32x4 __attribute__((ext_vector_type(4)));
typedef int v8i __attribute__((ext_vector_type(8)));

#define NB 8
#define ND 512
#define NT 2048
#define NCODES 4096
#define NM (NB * NT)
#define MARGIN_F 0.2f
#define ENC_STRIDE 320

// MX fragment image (Zq, Cq), fp8 e4m3:
//   tile (R_, K_) = 128 rows x 128 k = 16 KB at ((R_*4 + K_) * 16384)
//   fragment rg (0..7) = 16 rows x 128 k = 2048 B at rg*2048 within tile
//   bytes [0,1024): lane l's 16 B at l*16 = row rg*16+(l&15), k = (l>>4)*32 + 0..15
//   bytes [1024,2048): same lanes, k = (l>>4)*32 + 16..31

static __device__ inline void async_copy16(const void* g, void* l) {
    __builtin_amdgcn_global_load_lds(
        (const __attribute__((address_space(1))) unsigned int*)g,
        (__attribute__((address_space(3))) unsigned int*)l, 16, 0, 0);
}

static __device__ inline void stage8(const char* gA, const char* gB, char* dA, char* dB) {
#pragma unroll
    for (int i = 0; i < 4; i++) {
        async_copy16(gA + i * 1024, dA + i * 1024);
        async_copy16(gB + i * 1024, dB + i * 1024);
    }
}

// ---- kernel 1: fused prep. blocks [0,1024): student; [1024,1280): codebook ----
__global__ void prep_fused(const float* __restrict__ sf, const float* __restrict__ cb,
                           const int* __restrict__ lengths,
                           unsigned char* __restrict__ Zq, float* __restrict__ npart,
                           unsigned char* __restrict__ Cq, float* __restrict__ cnorm,
                           float* __restrict__ accum, unsigned int* __restrict__ ticket) {
    __shared__ float tile[128][65];
    __shared__ float redc[4][16];
    const int tid = threadIdx.x;  // 256
    const int wave = tid >> 6, lane = tid & 63, l15 = lane & 15, kq = lane >> 4;

    if (blockIdx.x < 1024) {
        const int bx = blockIdx.x;
        const int t0 = (bx & 31) * 64;
        const int d0 = ((bx >> 5) & 3) * 128;
        const int b = bx >> 7;
        if (t0 >= lengths[b] / ENC_STRIDE) return;  // fully-masked rows: output never used
        const float* src = sf + (size_t)b * ND * NT;
#pragma unroll
        for (int it = 0; it < 8; it++) {
            int idx = it * 256 + tid;
            int d = idx >> 4, t4 = (idx & 15) * 4;
            float4 v = *(const float4*)(src + (size_t)(d0 + d) * NT + t0 + t4);  // coalesced
            tile[d][t4] = v.x; tile[d][t4 + 1] = v.y; tile[d][t4 + 2] = v.z; tile[d][t4 + 3] = v.w;
        }
        __syncthreads();
        const int m0 = b * NT + t0;
        {
            const int trow = wave * 16 + l15;
            unsigned char q[32];
#pragma unroll
            for (int j = 0; j < 32; j += 2) {
                float a = tile[kq * 32 + j][trow];
                float c = tile[kq * 32 + j + 1][trow];
                int p = __builtin_amdgcn_cvt_pk_fp8_f32(a, c, 0, false);
                q[j] = (unsigned char)(p & 0xFF);
                q[j + 1] = (unsigned char)((p >> 8) & 0xFF);
            }
            const int M_ = m0 >> 7, rg = ((m0 >> 4) & 7) + wave, K_ = d0 >> 7;
            char* base = (char*)Zq + ((size_t)((M_ * 4 + K_) * 8 + rg)) * 2048;
            *(uint4*)(base + lane * 16) = *(uint4*)&q[0];
            *(uint4*)(base + 1024 + lane * 16) = *(uint4*)&q[16];
        }
        if (tid < 64) {
            float s = 0.0f;
#pragma unroll 16
            for (int d = 0; d < 128; d++) {
                float v = tile[d][tid];
                s += v * v;
            }
            npart[(size_t)(d0 >> 7) * NM + m0 + tid] = s;
        }
    } else {
        if (blockIdx.x == 1279 && tid == 0) { *accum = 0.0f; *ticket = 0u; }
        const int r0 = (blockIdx.x - 1024) * 16;
        const int row = r0 + l15;
        const int K_ = wave;  // each wave handles one 128-k quarter
        const float* src = cb + (size_t)row * ND + K_ * 128 + kq * 32;
        unsigned char q[32];
        float s = 0.0f;
#pragma unroll
        for (int j4 = 0; j4 < 8; j4++) {
            float4 v = *(const float4*)(src + j4 * 4);
            s += v.x * v.x + v.y * v.y + v.z * v.z + v.w * v.w;
            int p0 = __builtin_amdgcn_cvt_pk_fp8_f32(v.x, v.y, 0, false);
            int p1 = __builtin_amdgcn_cvt_pk_fp8_f32(v.z, v.w, 0, false);
            q[j4 * 4 + 0] = (unsigned char)(p0 & 0xFF);
            q[j4 * 4 + 1] = (unsigned char)((p0 >> 8) & 0xFF);
            q[j4 * 4 + 2] = (unsigned char)(p1 & 0xFF);
            q[j4 * 4 + 3] = (unsigned char)((p1 >> 8) & 0xFF);
        }
        const int N_ = r0 >> 7, rg = (r0 >> 4) & 7;
        char* base = (char*)Cq + ((size_t)((N_ * 4 + K_) * 8 + rg)) * 2048;
        *(uint4*)(base + lane * 16) = *(uint4*)&q[0];
        *(uint4*)(base + 1024 + lane * 16) = *(uint4*)&q[16];
        s += __shfl_xor(s, 16);
        s += __shfl_xor(s, 32);
        if (lane < 16) redc[wave][l15] = s;
        __syncthreads();
        if (tid < 16) cnorm[r0 + tid] = redc[0][tid] + redc[1][tid] + redc[2][tid] + redc[3][tid];
    }
}

// ---- kernel 2: MX-fp8 GEMM with COUNTED-vmcnt pipeline (T3+T4+T5) ----
// Tile stream u = nt*4+kt (0..15), double-buffered LDS (cur = u&1).
// Per tile: issue L(u+1) -> buf[cur^1]; s_waitcnt vmcnt(8) (own L(u) done, L(u+1)'s
// 8 stay IN FLIGHT across the barrier -- never drain to 0 in the loop); s_barrier
// (peers' L(u) done); ds_read buf[cur] + MFMA (setprio 1); s_barrier (reads done,
// buf[cur] free for L(u+2)). Raw s_barrier, NOT __syncthreads: hipcc's barrier
// drain (vmcnt(0)) was the 16x-per-block stall in R0/R1.
__global__ __launch_bounds__(256, 2) void triplet_main(
    const unsigned char* __restrict__ Zq, const unsigned char* __restrict__ Cq,
    const float* __restrict__ cnorm, const int* __restrict__ teacher,
    const int* __restrict__ lengths,
    float* __restrict__ negq, float* __restrict__ posq) {
    __shared__ __align__(16) unsigned char As[2][16384];
    __shared__ __align__(16) unsigned char Bs[2][16384];

    const int M_ = blockIdx.x;   // x-major => XCD = M_ % 8: strip-local L2 reuse
    const int m0 = M_ * 128;
    // fully-masked M-tile: reduce_final selects 0 for every row here; skip all work.
    const int flen = lengths[m0 >> 11] / ENC_STRIDE;
    if ((m0 & (NT - 1)) >= flen) return;

    const int nq = blockIdx.y;   // 0..7
    const int tid = threadIdx.x;
    const int wave = tid >> 6, lane = tid & 63;
    const int wr = wave >> 1, wc = wave & 1;
    const int l15 = lane & 15, quad = lane >> 4;

    const float INF = __builtin_inff();

    // Pre-pin teacher + cnorm into registers: no global loads inside the pipelined
    // loop (a compiler-inserted wait for them would drain our in-flight stages).
    int tch[4][4];
    float cn[4][4];
#pragma unroll
    for (int mi = 0; mi < 4; mi++)
#pragma unroll
        for (int r = 0; r < 4; r++)
            tch[mi][r] = teacher[m0 + wr * 64 + mi * 16 + quad * 4 + r];
#pragma unroll
    for (int nt = 0; nt < 4; nt++)
#pragma unroll
        for (int ni = 0; ni < 4; ni++)
            cn[nt][ni] = cnorm[(nq * 4 + nt) * 128 + wc * 64 + ni * 16 + l15];
#pragma unroll
    for (int mi = 0; mi < 4; mi++)
#pragma unroll
        for (int r = 0; r < 4; r++) {
            asm volatile("" : "+v"(tch[mi][r]));
            asm volatile("" : "+v"(cn[mi][r]));
        }

    float minv[4][4], posv[4][4];
#pragma unroll
    for (int mi = 0; mi < 4; mi++)
#pragma unroll
        for (int r = 0; r < 4; r++) { minv[mi][r] = INF; posv[mi][r] = INF; }

    const int ldsoff = wave * 4096;
    const char* gA0 = (const char*)Zq + (size_t)M_ * 4 * 16384 + ldsoff + lane * 16;
    const char* gB0 = (const char*)Cq + (size_t)nq * 16 * 16384 + ldsoff + lane * 16;
    char* dA0 = (char*)As[0] + ldsoff;
    char* dA1 = (char*)As[1] + ldsoff;
    char* dB0 = (char*)Bs[0] + ldsoff;
    char* dB1 = (char*)Bs[1] + ldsoff;

    stage8(gA0, gB0, dA0, dB0);  // L(0) -> buf0

#pragma unroll
    for (int nt = 0; nt < 4; ++nt) {
        f32x4 acc[4][4];
#pragma unroll
        for (int mi = 0; mi < 4; mi++)
#pragma unroll
            for (int ni = 0; ni < 4; ni++)
                acc[mi][ni] = (f32x4){0.f, 0.f, 0.f, 0.f};

#pragma unroll
        for (int kt = 0; kt < 4; ++kt) {
            // ---- A: prefetch next tile into the other buffer, counted wait ----
            if (nt < 3 || kt < 3) {
                const char* gA = gA0 + (size_t)((kt + 1) & 3) * 16384;
                const char* gB = gB0 + (size_t)(nt * 4 + kt + 1) * 16384;
                stage8(gA, gB, (kt & 1) ? dA0 : dA1, (kt & 1) ? dB0 : dB1);
                asm volatile("s_waitcnt vmcnt(8)" ::: "memory");  // L(u) landed; L(u+1) in flight
            } else {
                asm volatile("s_waitcnt vmcnt(0)" ::: "memory");  // final tile only
            }
            __builtin_amdgcn_s_barrier();        // all waves' L(u) landed
            __builtin_amdgcn_sched_barrier(0);   // no ds_read hoists above this point

            // ---- D: fragments + MFMA ----
            const unsigned char* sA = As[kt & 1];
            const unsigned char* sB = Bs[kt & 1];
            v8i av[4], bv[4];
#pragma unroll
            for (int mi = 0; mi < 4; mi++) {
                int rg = wr * 4 + mi;
                union { uint4 q[2]; v8i v; } uu;
                uu.q[0] = *(const uint4*)(sA + rg * 2048 + lane * 16);
                uu.q[1] = *(const uint4*)(sA + rg * 2048 + 1024 + lane * 16);
                av[mi] = uu.v;
            }
#pragma unroll
            for (int ni = 0; ni < 4; ni++) {
                int rg = wc * 4 + ni;
                union { uint4 q[2]; v8i v; } uu;
                uu.q[0] = *(const uint4*)(sB + rg * 2048 + lane * 16);
                uu.q[1] = *(const uint4*)(sB + rg * 2048 + 1024 + lane * 16);
                bv[ni] = uu.v;
            }
            __builtin_amdgcn_s_setprio(1);
#pragma unroll
            for (int mi = 0; mi < 4; mi++)
#pragma unroll
                for (int ni = 0; ni < 4; ni++)
                    acc[mi][ni] = __builtin_amdgcn_mfma_scale_f32_16x16x128_f8f6f4(
                        av[mi], bv[ni], acc[mi][ni], 0, 0,
                        0, 0x7F7F7F7F, 0, 0x7F7F7F7F);  // scales = 1.0 (e8m0 127)
            __builtin_amdgcn_s_setprio(0);

            __builtin_amdgcn_s_barrier();        // E: reads of buf[cur] done -> reusable
        }

        // ---- fold nt (registers only) ----
        const int n0 = (nq * 4 + nt) * 128;
#pragma unroll
        for (int mi = 0; mi < 4; mi++)
#pragma unroll
            for (int r = 0; r < 4; r++) {
                int t = tch[mi][r];
#pragma unroll
                for (int ni = 0; ni < 4; ni++) {
                    float val = fmaf(-2.0f, acc[mi][ni][r], cn[nt][ni]);
                    int colv = n0 + wc * 64 + ni * 16 + l15;
                    bool ist = (colv == t);
                    minv[mi][r] = fminf(minv[mi][r], ist ? INF : val);
                    posv[mi][r] = fminf(posv[mi][r], ist ? val : INF);
                }
            }
    }

    const int slot = nq * 2 + wc;  // 0..15
#pragma unroll
    for (int mi = 0; mi < 4; mi++)
#pragma unroll
        for (int r = 0; r < 4; r++) {
            float mn = minv[mi][r], ps = posv[mi][r];
#pragma unroll
            for (int off = 1; off < 16; off <<= 1) {
                mn = fminf(mn, __shfl_xor(mn, off));
                ps = fminf(ps, __shfl_xor(ps, off));
            }
            if (l15 == 0) {
                int m = m0 + wr * 64 + mi * 16 + quad * 4 + r;
                negq[(size_t)slot * NM + m] = mn;
                posq[(size_t)slot * NM + m] = ps;
            }
        }
}

// ---- kernel 3: per-row reduce over 16 slots + ticketed finalize (64 blocks only) ----
__global__ void reduce_final(const float* __restrict__ negq, const float* __restrict__ posq,
                             const float* __restrict__ npart, const int* __restrict__ lengths,
                             float* __restrict__ accum, unsigned int* __restrict__ ticket,
                             float* __restrict__ out) {
    const float INF = __builtin_inff();
    const int m = blockIdx.x * 256 + threadIdx.x;
    float mn = INF, ps = INF;
#pragma unroll
    for (int s = 0; s < 16; s++) {
        mn = fminf(mn, negq[(size_t)s * NM + m]);  // coalesced
        ps = fminf(ps, posq[(size_t)s * NM + m]);
    }
    float zn = npart[m] + npart[NM + m] + npart[2 * NM + m] + npart[3 * NM + m];
    float negd = sqrtf(fmaxf(zn + mn, 1e-12f));
    float posd = sqrtf(fmaxf(zn + ps, 1e-12f));
    float tri = fmaxf(posd - negd + MARGIN_F, 0.0f);
    int b = m >> 11;
    int tt = m & (NT - 1);
    int flen = lengths[b] / ENC_STRIDE;
    float val = (tt < flen) ? tri : 0.0f;  // select (not multiply): NaN/garbage-safe

    __shared__ float red[4];
#pragma unroll
    for (int off = 1; off < 64; off <<= 1) val += __shfl_xor(val, off);
    int lane = threadIdx.x & 63, w = threadIdx.x >> 6;
    if (lane == 0) red[w] = val;
    __syncthreads();
    if (threadIdx.x == 0) {
        atomicAdd(accum, red[0] + red[1] + red[2] + red[3]);
        __threadfence();
        unsigned int old = atomicAdd(ticket, 1u);
        if (old == 63u) {  // last block: all adds are visible
            float total = atomicAdd(accum, 0.0f);
            float cnt = 0.0f;
            for (int bb = 0; bb < NB; bb++) cnt += (float)(lengths[bb] / ENC_STRIDE);
            out[0] = total / (cnt + 1e-8f);
        }
    }
}

extern "C" void kernel_launch(void* const* d_in, const int* in_sizes, int n_in,
                              void* d_out, int out_size, void* d_ws, size_t ws_size,
                              hipStream_t stream) {
    const float* sf = (const float*)d_in[0];
    const int* teacher = (const int*)d_in[1];
    const float* cb = (const float*)d_in[2];
    const int* lengths = (const int*)d_in[3];

    char* ws = (char*)d_ws;
    unsigned char* Zq = (unsigned char*)(ws);                  //  8,388,608 B
    unsigned char* Cq = (unsigned char*)(ws + 8388608);        //  2,097,152 B
    float* cnorm = (float*)(ws + 10485760);                    //     16,384 B
    float* npart = (float*)(ws + 10502144);                    //    262,144 B (4 x NM)
    float* negq = (float*)(ws + 10764288);                     //  1,048,576 B (16 x NM)
    float* posq = (float*)(ws + 11812864);                     //  1,048,576 B
    float* accum = (float*)(ws + 12861440);                    //          4 B
    unsigned int* ticket = (unsigned int*)(ws + 12861444);     //          4 B

    prep_fused<<<1280, 256, 0, stream>>>(sf, cb, lengths, Zq, npart, Cq, cnorm, accum, ticket);
    triplet_main<<<dim3(128, 8), 256, 0, stream>>>(Zq, Cq, cnorm, teacher, lengths, negq, posq);
    reduce_final<<<64, 256, 0, stream>>>(negq, posq, npart, lengths, accum, ticket,
                                         (float*)d_out);
}

// Round 3
// 222.396 us; speedup vs baseline: 2.5990x; 2.5990x over previous
//
#include <hip/hip_runtime.h>
#include <hip/hip_bf16.h>

typedef float f32x4 __attribute__((ext_vector_type(4)));
typedef int v8i __attribute__((ext_vector_type(8)));

#define NB 8
#define ND 512
#define NT 2048
#define NCODES 4096
#define NM (NB * NT)
#define MARGIN_F 0.2f
#define ENC_STRIDE 320

// MX fragment image (Zq, Cq), fp8 e4m3:
//   tile (R_, K_) = 128 rows x 128 k = 16 KB at ((R_*4 + K_) * 16384)
//   fragment rg (0..7) = 16 rows x 128 k = 2048 B at rg*2048 within tile
//   bytes [0,1024): lane l's 16 B at l*16 = row rg*16+(l&15), k = (l>>4)*32 + 0..15
//   bytes [1024,2048): same lanes, k = (l>>4)*32 + 16..31

static __device__ inline void async_copy16(const void* g, void* l) {
    __builtin_amdgcn_global_load_lds(
        (const __attribute__((address_space(1))) unsigned int*)g,
        (__attribute__((address_space(3))) unsigned int*)l, 16, 0, 0);
}

static __device__ inline void stage8(const char* gA, const char* gB, char* dA, char* dB) {
#pragma unroll
    for (int i = 0; i < 4; i++) {
        async_copy16(gA + i * 1024, dA + i * 1024);
        async_copy16(gB + i * 1024, dB + i * 1024);
    }
}

// ---- kernel 1: fused prep. blocks [0,1024): student; [1024,1280): codebook ----
__global__ void prep_fused(const float* __restrict__ sf, const float* __restrict__ cb,
                           const int* __restrict__ lengths,
                           unsigned char* __restrict__ Zq, float* __restrict__ npart,
                           unsigned char* __restrict__ Cq, float* __restrict__ cnorm,
                           float* __restrict__ accum, unsigned int* __restrict__ ticket) {
    __shared__ float tile[128][65];
    __shared__ float redc[4][16];
    const int tid = threadIdx.x;  // 256
    const int wave = tid >> 6, lane = tid & 63, l15 = lane & 15, kq = lane >> 4;

    if (blockIdx.x < 1024) {
        const int bx = blockIdx.x;
        const int t0 = (bx & 31) * 64;
        const int d0 = ((bx >> 5) & 3) * 128;
        const int b = bx >> 7;
        if (t0 >= lengths[b] / ENC_STRIDE) return;  // fully-masked rows: output never used
        const float* src = sf + (size_t)b * ND * NT;
#pragma unroll
        for (int it = 0; it < 8; it++) {
            int idx = it * 256 + tid;
            int d = idx >> 4, t4 = (idx & 15) * 4;
            float4 v = *(const float4*)(src + (size_t)(d0 + d) * NT + t0 + t4);  // coalesced
            tile[d][t4] = v.x; tile[d][t4 + 1] = v.y; tile[d][t4 + 2] = v.z; tile[d][t4 + 3] = v.w;
        }
        __syncthreads();
        const int m0 = b * NT + t0;
        {
            const int trow = wave * 16 + l15;
            unsigned char q[32];
#pragma unroll
            for (int j = 0; j < 32; j += 2) {
                float a = tile[kq * 32 + j][trow];
                float c = tile[kq * 32 + j + 1][trow];
                int p = __builtin_amdgcn_cvt_pk_fp8_f32(a, c, 0, false);
                q[j] = (unsigned char)(p & 0xFF);
                q[j + 1] = (unsigned char)((p >> 8) & 0xFF);
            }
            const int M_ = m0 >> 7, rg = ((m0 >> 4) & 7) + wave, K_ = d0 >> 7;
            char* base = (char*)Zq + ((size_t)((M_ * 4 + K_) * 8 + rg)) * 2048;
            *(uint4*)(base + lane * 16) = *(uint4*)&q[0];
            *(uint4*)(base + 1024 + lane * 16) = *(uint4*)&q[16];
        }
        if (tid < 64) {
            float s = 0.0f;
#pragma unroll 16
            for (int d = 0; d < 128; d++) {
                float v = tile[d][tid];
                s += v * v;
            }
            npart[(size_t)(d0 >> 7) * NM + m0 + tid] = s;
        }
    } else {
        if (blockIdx.x == 1279 && tid == 0) { *accum = 0.0f; *ticket = 0u; }
        const int r0 = (blockIdx.x - 1024) * 16;
        const int row = r0 + l15;
        const int K_ = wave;  // each wave handles one 128-k quarter
        const float* src = cb + (size_t)row * ND + K_ * 128 + kq * 32;
        unsigned char q[32];
        float s = 0.0f;
#pragma unroll
        for (int j4 = 0; j4 < 8; j4++) {
            float4 v = *(const float4*)(src + j4 * 4);
            s += v.x * v.x + v.y * v.y + v.z * v.z + v.w * v.w;
            int p0 = __builtin_amdgcn_cvt_pk_fp8_f32(v.x, v.y, 0, false);
            int p1 = __builtin_amdgcn_cvt_pk_fp8_f32(v.z, v.w, 0, false);
            q[j4 * 4 + 0] = (unsigned char)(p0 & 0xFF);
            q[j4 * 4 + 1] = (unsigned char)((p0 >> 8) & 0xFF);
            q[j4 * 4 + 2] = (unsigned char)(p1 & 0xFF);
            q[j4 * 4 + 3] = (unsigned char)((p1 >> 8) & 0xFF);
        }
        const int N_ = r0 >> 7, rg = (r0 >> 4) & 7;
        char* base = (char*)Cq + ((size_t)((N_ * 4 + K_) * 8 + rg)) * 2048;
        *(uint4*)(base + lane * 16) = *(uint4*)&q[0];
        *(uint4*)(base + 1024 + lane * 16) = *(uint4*)&q[16];
        s += __shfl_xor(s, 16);
        s += __shfl_xor(s, 32);
        if (lane < 16) redc[wave][l15] = s;
        __syncthreads();
        if (tid < 16) cnorm[r0 + tid] = redc[0][tid] + redc[1][tid] + redc[2][tid] + redc[3][tid];
    }
}

// ---- kernel 2: MX-fp8 GEMM, counted-vmcnt pipeline (spill-proofed) ----
// Tile stream u = nt*4+kt. Buffer parity u&1 == kt&1 (nt*4 is even), so buffers are
// STATIC inside the unrolled kt loop while the nt loop stays dynamic (unroll 1) --
// short live ranges, no spill (R2's full unroll + reg pins spilled 609 MB to scratch).
// Per tile: stage L(u+1) -> buf[kt^1]; vmcnt(8) (own L(u) landed, L(u+1)'s 8 stay in
// flight ACROSS the barriers); s_barrier; ds_read buf[kt&1]; MFMA (setprio 1);
// s_barrier. Own ds_reads complete before the post-MFMA barrier (MFMA uses force
// lgkmcnt), so staging into that buffer after the barrier is race-free.
__global__ __launch_bounds__(256, 2) void triplet_main(
    const unsigned char* __restrict__ Zq, const unsigned char* __restrict__ Cq,
    const float* __restrict__ cnorm, const int* __restrict__ teacher,
    const int* __restrict__ lengths,
    float* __restrict__ negq, float* __restrict__ posq) {
    __shared__ __align__(16) unsigned char As[2][16384];
    __shared__ __align__(16) unsigned char Bs[2][16384];

    const int M_ = blockIdx.x;   // x-major => XCD = M_ % 8: strip-local L2 reuse
    const int m0 = M_ * 128;
    // fully-masked M-tile: reduce_final selects 0 for every row here; skip all work.
    const int flen = lengths[m0 >> 11] / ENC_STRIDE;
    if ((m0 & (NT - 1)) >= flen) return;

    const int nq = blockIdx.y;   // 0..7
    const int tid = threadIdx.x;
    const int wave = tid >> 6, lane = tid & 63;
    const int wr = wave >> 1, wc = wave & 1;
    const int l15 = lane & 15, quad = lane >> 4;

    const float INF = __builtin_inff();

    // Preload teacher + cnorm, then drain ONCE before the pipeline starts: no
    // global-load waits can then land inside the loop and flush in-flight stages.
    int tch[4][4];
    float cn[4][4];
#pragma unroll
    for (int mi = 0; mi < 4; mi++)
#pragma unroll
        for (int r = 0; r < 4; r++)
            tch[mi][r] = teacher[m0 + wr * 64 + mi * 16 + quad * 4 + r];
#pragma unroll
    for (int nt = 0; nt < 4; nt++)
#pragma unroll
        for (int ni = 0; ni < 4; ni++)
            cn[nt][ni] = cnorm[(nq * 4 + nt) * 128 + wc * 64 + ni * 16 + l15];
    asm volatile("s_waitcnt vmcnt(0)" ::: "memory");  // all scalar preloads landed

    float minv[4][4], posv[4][4];
#pragma unroll
    for (int mi = 0; mi < 4; mi++)
#pragma unroll
        for (int r = 0; r < 4; r++) { minv[mi][r] = INF; posv[mi][r] = INF; }

    const int ldsoff = wave * 4096;
    const char* gA0 = (const char*)Zq + (size_t)M_ * 4 * 16384 + ldsoff + lane * 16;
    const char* gB0 = (const char*)Cq + (size_t)nq * 16 * 16384 + ldsoff + lane * 16;
    char* dA0 = (char*)As[0] + ldsoff;
    char* dA1 = (char*)As[1] + ldsoff;
    char* dB0 = (char*)Bs[0] + ldsoff;
    char* dB1 = (char*)Bs[1] + ldsoff;

    stage8(gA0, gB0, dA0, dB0);  // L(0) -> buf0 (8 loads in flight)

#pragma unroll 1
    for (int nt = 0; nt < 4; ++nt) {
        f32x4 acc[4][4];
#pragma unroll
        for (int mi = 0; mi < 4; mi++)
#pragma unroll
            for (int ni = 0; ni < 4; ni++)
                acc[mi][ni] = (f32x4){0.f, 0.f, 0.f, 0.f};

#pragma unroll
        for (int kt = 0; kt < 4; ++kt) {
            // ---- stage next tile into other buffer; counted wait ----
            if (nt < 3 || kt < 3) {
                const int un = nt * 4 + kt + 1;
                stage8(gA0 + (size_t)(un & 3) * 16384, gB0 + (size_t)un * 16384,
                       (kt & 1) ? dA0 : dA1, (kt & 1) ? dB0 : dB1);
                asm volatile("s_waitcnt vmcnt(8)" ::: "memory");  // L(u) done; L(u+1) in flight
            } else {
                asm volatile("s_waitcnt vmcnt(0)" ::: "memory");  // last tile only
            }
            __builtin_amdgcn_s_barrier();        // peers' L(u) landed
            __builtin_amdgcn_sched_barrier(0);   // no ds_read hoists above barrier

            // ---- fragments + MFMA from buf[kt&1] ----
            const unsigned char* sA = As[kt & 1];
            const unsigned char* sB = Bs[kt & 1];
            v8i av[4], bv[4];
#pragma unroll
            for (int mi = 0; mi < 4; mi++) {
                int rg = wr * 4 + mi;
                union { uint4 q[2]; v8i v; } uu;
                uu.q[0] = *(const uint4*)(sA + rg * 2048 + lane * 16);
                uu.q[1] = *(const uint4*)(sA + rg * 2048 + 1024 + lane * 16);
                av[mi] = uu.v;
            }
#pragma unroll
            for (int ni = 0; ni < 4; ni++) {
                int rg = wc * 4 + ni;
                union { uint4 q[2]; v8i v; } uu;
                uu.q[0] = *(const uint4*)(sB + rg * 2048 + lane * 16);
                uu.q[1] = *(const uint4*)(sB + rg * 2048 + 1024 + lane * 16);
                bv[ni] = uu.v;
            }
            __builtin_amdgcn_s_setprio(1);
#pragma unroll
            for (int mi = 0; mi < 4; mi++)
#pragma unroll
                for (int ni = 0; ni < 4; ni++)
                    acc[mi][ni] = __builtin_amdgcn_mfma_scale_f32_16x16x128_f8f6f4(
                        av[mi], bv[ni], acc[mi][ni], 0, 0,
                        0, 0x7F7F7F7F, 0, 0x7F7F7F7F);  // scales = 1.0 (e8m0 127)
            __builtin_amdgcn_s_setprio(0);

            __builtin_amdgcn_s_barrier();        // reads of buf[kt&1] complete -> reusable
            __builtin_amdgcn_sched_barrier(0);   // next stage must not hoist above
        }

        // ---- fold nt (registers only) ----
        const int n0 = (nq * 4 + nt) * 128;
#pragma unroll
        for (int mi = 0; mi < 4; mi++)
#pragma unroll
            for (int r = 0; r < 4; r++) {
                int t = tch[mi][r];
#pragma unroll
                for (int ni = 0; ni < 4; ni++) {
                    float val = fmaf(-2.0f, acc[mi][ni][r], cn[nt][ni]);
                    int colv = n0 + wc * 64 + ni * 16 + l15;
                    bool ist = (colv == t);
                    minv[mi][r] = fminf(minv[mi][r], ist ? INF : val);
                    posv[mi][r] = fminf(posv[mi][r], ist ? val : INF);
                }
            }
    }

    const int slot = nq * 2 + wc;  // 0..15
#pragma unroll
    for (int mi = 0; mi < 4; mi++)
#pragma unroll
        for (int r = 0; r < 4; r++) {
            float mn = minv[mi][r], ps = posv[mi][r];
#pragma unroll
            for (int off = 1; off < 16; off <<= 1) {
                mn = fminf(mn, __shfl_xor(mn, off));
                ps = fminf(ps, __shfl_xor(ps, off));
            }
            if (l15 == 0) {
                int m = m0 + wr * 64 + mi * 16 + quad * 4 + r;
                negq[(size_t)slot * NM + m] = mn;
                posq[(size_t)slot * NM + m] = ps;
            }
        }
}

// ---- kernel 3: per-row reduce over 16 slots + ticketed finalize (64 blocks only) ----
__global__ void reduce_final(const float* __restrict__ negq, const float* __restrict__ posq,
                             const float* __restrict__ npart, const int* __restrict__ lengths,
                             float* __restrict__ accum, unsigned int* __restrict__ ticket,
                             float* __restrict__ out) {
    const float INF = __builtin_inff();
    const int m = blockIdx.x * 256 + threadIdx.x;
    float mn = INF, ps = INF;
#pragma unroll
    for (int s = 0; s < 16; s++) {
        mn = fminf(mn, negq[(size_t)s * NM + m]);  // coalesced
        ps = fminf(ps, posq[(size_t)s * NM + m]);
    }
    float zn = npart[m] + npart[NM + m] + npart[2 * NM + m] + npart[3 * NM + m];
    float negd = sqrtf(fmaxf(zn + mn, 1e-12f));
    float posd = sqrtf(fmaxf(zn + ps, 1e-12f));
    float tri = fmaxf(posd - negd + MARGIN_F, 0.0f);
    int b = m >> 11;
    int tt = m & (NT - 1);
    int flen = lengths[b] / ENC_STRIDE;
    float val = (tt < flen) ? tri : 0.0f;  // select (not multiply): NaN/garbage-safe

    __shared__ float red[4];
#pragma unroll
    for (int off = 1; off < 64; off <<= 1) val += __shfl_xor(val, off);
    int lane = threadIdx.x & 63, w = threadIdx.x >> 6;
    if (lane == 0) red[w] = val;
    __syncthreads();
    if (threadIdx.x == 0) {
        atomicAdd(accum, red[0] + red[1] + red[2] + red[3]);
        __threadfence();
        unsigned int old = atomicAdd(ticket, 1u);
        if (old == 63u) {  // last block: all adds are visible
            float total = atomicAdd(accum, 0.0f);
            float cnt = 0.0f;
            for (int bb = 0; bb < NB; bb++) cnt += (float)(lengths[bb] / ENC_STRIDE);
            out[0] = total / (cnt + 1e-8f);
        }
    }
}

extern "C" void kernel_launch(void* const* d_in, const int* in_sizes, int n_in,
                              void* d_out, int out_size, void* d_ws, size_t ws_size,
                              hipStream_t stream) {
    const float* sf = (const float*)d_in[0];
    const int* teacher = (const int*)d_in[1];
    const float* cb = (const float*)d_in[2];
    const int* lengths = (const int*)d_in[3];

    char* ws = (char*)d_ws;
    unsigned char* Zq = (unsigned char*)(ws);                  //  8,388,608 B
    unsigned char* Cq = (unsigned char*)(ws + 8388608);        //  2,097,152 B
    float* cnorm = (float*)(ws + 10485760);                    //     16,384 B
    float* npart = (float*)(ws + 10502144);                    //    262,144 B (4 x NM)
    float* negq = (float*)(ws + 10764288);                     //  1,048,576 B (16 x NM)
    float* posq = (float*)(ws + 11812864);                     //  1,048,576 B
    float* accum = (float*)(ws + 12861440);                    //          4 B
    unsigned int* ticket = (unsigned int*)(ws + 12861444);     //          4 B

    prep_fused<<<1280, 256, 0, stream>>>(sf, cb, lengths, Zq, npart, Cq, cnorm, accum, ticket);
    triplet_main<<<dim3(128, 8), 256, 0, stream>>>(Zq, Cq, cnorm, teacher, lengths, negq, posq);
    reduce_final<<<64, 256, 0, stream>>>(negq, posq, npart, lengths, accum, ticket,
                                         (float*)d_out);
}

// Round 4
// 133.358 us; speedup vs baseline: 4.3343x; 1.6677x over previous
//
#include <hip/hip_runtime.h>
#include <hip/hip_bf16.h>

typedef float f32x4 __attribute__((ext_vector_type(4)));
typedef int v8i __attribute__((ext_vector_type(8)));

#define NB 8
#define ND 512
#define NT 2048
#define NCODES 4096
#define NM (NB * NT)
#define MARGIN_F 0.2f
#define ENC_STRIDE 320

// MX fragment image (Zq, Cq), fp8 e4m3:
//   tile (R_, K_) = 128 rows x 128 k = 16 KB at ((R_*4 + K_) * 16384)
//   fragment rg (0..7) = 16 rows x 128 k = 2048 B at rg*2048 within tile
//   bytes [0,1024): lane l's 16 B at l*16 = row rg*16+(l&15), k = (l>>4)*32 + 0..15
//   bytes [1024,2048): same lanes, k = (l>>4)*32 + 16..31

static __device__ inline void async_copy16(const void* g, void* l) {
    __builtin_amdgcn_global_load_lds(
        (const __attribute__((address_space(1))) unsigned int*)g,
        (__attribute__((address_space(3))) unsigned int*)l, 16, 0, 0);
}

// Map a linear rank to the rank-th SURVIVING tile (tiles of 2^shift rows within each
// batch's valid prefix). Survivor compaction: makes live blocks contiguous in
// blockIdx -> uniform CU/XCD distribution (raw grid order clusters all-alive /
// all-dead runs onto the same CUs; that imbalance was the real cost of masking).
static __device__ inline bool rank_decode(const int* __restrict__ lengths, int rank,
                                          int shift, int& b, int& tib) {
    int acc = 0;
    bool ok = false;
#pragma unroll
    for (int bb = 0; bb < NB; bb++) {
        int fl = lengths[bb] / ENC_STRIDE;
        int c = (fl + ((1 << shift) - 1)) >> shift;  // ceil(fl / tile_rows)
        if (!ok && rank < acc + c) { b = bb; tib = rank - acc; ok = true; }
        acc += c;
    }
    return ok;
}

// ---- kernel 1: fused prep. blocks [0,1024): student (compacted); [1024,1280): codebook ----
__global__ void prep_fused(const float* __restrict__ sf, const float* __restrict__ cb,
                           const int* __restrict__ lengths,
                           unsigned char* __restrict__ Zq, float* __restrict__ npart,
                           unsigned char* __restrict__ Cq, float* __restrict__ cnorm,
                           float* __restrict__ accum, unsigned int* __restrict__ ticket) {
    __shared__ float tile[128][65];
    __shared__ float redc[4][16];
    const int tid = threadIdx.x;  // 256
    const int wave = tid >> 6, lane = tid & 63, l15 = lane & 15, kq = lane >> 4;

    if (blockIdx.x < 1024) {
        const int bx = blockIdx.x;
        int b, tt;
        if (!rank_decode(lengths, bx >> 2, 6, b, tt)) return;  // 64-row student tiles
        const int t0 = tt * 64;
        const int d0 = (bx & 3) * 128;
        const float* src = sf + (size_t)b * ND * NT;
#pragma unroll
        for (int it = 0; it < 8; it++) {
            int idx = it * 256 + tid;
            int d = idx >> 4, t4 = (idx & 15) * 4;
            float4 v = *(const float4*)(src + (size_t)(d0 + d) * NT + t0 + t4);  // coalesced
            tile[d][t4] = v.x; tile[d][t4 + 1] = v.y; tile[d][t4 + 2] = v.z; tile[d][t4 + 3] = v.w;
        }
        __syncthreads();
        const int m0 = b * NT + t0;
        {
            const int trow = wave * 16 + l15;
            unsigned char q[32];
#pragma unroll
            for (int j = 0; j < 32; j += 2) {
                float a = tile[kq * 32 + j][trow];
                float c = tile[kq * 32 + j + 1][trow];
                int p = __builtin_amdgcn_cvt_pk_fp8_f32(a, c, 0, false);
                q[j] = (unsigned char)(p & 0xFF);
                q[j + 1] = (unsigned char)((p >> 8) & 0xFF);
            }
            const int M_ = m0 >> 7, rg = ((m0 >> 4) & 7) + wave, K_ = d0 >> 7;
            char* base = (char*)Zq + ((size_t)((M_ * 4 + K_) * 8 + rg)) * 2048;
            *(uint4*)(base + lane * 16) = *(uint4*)&q[0];
            *(uint4*)(base + 1024 + lane * 16) = *(uint4*)&q[16];
        }
        if (tid < 64) {
            float s = 0.0f;
#pragma unroll 16
            for (int d = 0; d < 128; d++) {
                float v = tile[d][tid];
                s += v * v;
            }
            npart[(size_t)(d0 >> 7) * NM + m0 + tid] = s;
        }
    } else {
        if (blockIdx.x == 1279 && tid == 0) { *accum = 0.0f; *ticket = 0u; }
        const int r0 = (blockIdx.x - 1024) * 16;
        const int row = r0 + l15;
        const int K_ = wave;  // each wave handles one 128-k quarter
        const float* src = cb + (size_t)row * ND + K_ * 128 + kq * 32;
        unsigned char q[32];
        float s = 0.0f;
#pragma unroll
        for (int j4 = 0; j4 < 8; j4++) {
            float4 v = *(const float4*)(src + j4 * 4);
            s += v.x * v.x + v.y * v.y + v.z * v.z + v.w * v.w;
            int p0 = __builtin_amdgcn_cvt_pk_fp8_f32(v.x, v.y, 0, false);
            int p1 = __builtin_amdgcn_cvt_pk_fp8_f32(v.z, v.w, 0, false);
            q[j4 * 4 + 0] = (unsigned char)(p0 & 0xFF);
            q[j4 * 4 + 1] = (unsigned char)((p0 >> 8) & 0xFF);
            q[j4 * 4 + 2] = (unsigned char)(p1 & 0xFF);
            q[j4 * 4 + 3] = (unsigned char)((p1 >> 8) & 0xFF);
        }
        const int N_ = r0 >> 7, rg = (r0 >> 4) & 7;
        char* base = (char*)Cq + ((size_t)((N_ * 4 + K_) * 8 + rg)) * 2048;
        *(uint4*)(base + lane * 16) = *(uint4*)&q[0];
        *(uint4*)(base + 1024 + lane * 16) = *(uint4*)&q[16];
        s += __shfl_xor(s, 16);
        s += __shfl_xor(s, 32);
        if (lane < 16) redc[wave][l15] = s;
        __syncthreads();
        if (tid < 16) cnorm[r0 + tid] = redc[0][tid] + redc[1][tid] + redc[2][tid] + redc[3][tid];
    }
}

// ---- kernel 2: MX-fp8 GEMM (R1's proven dbuf body; compacted rank decode) ----
// rank = blockIdx.x: m_rank = rank>>3 (compacted surviving M-tile), nq = rank&7.
// Same-nq blocks land on the same XCD (blk%8==nq) -> Cq quarter (256 KB) L2-resident.
// Loop body verbatim from R1 (52.2 us, no spill): __syncthreads 2-phase, issue-early
// prefetch into the other buffer. Inline-asm counted-vmcnt variants (R2/R3) spilled
// acc to scratch (126-609 MB) on this 4-wave geometry -- do not reintroduce.
__global__ __launch_bounds__(256, 2) void triplet_main(
    const unsigned char* __restrict__ Zq, const unsigned char* __restrict__ Cq,
    const float* __restrict__ cnorm, const int* __restrict__ teacher,
    const int* __restrict__ lengths,
    float* __restrict__ negq, float* __restrict__ posq) {
    __shared__ __align__(16) unsigned char As[2][16384];
    __shared__ __align__(16) unsigned char Bs[2][16384];

    int b, tM;
    if (!rank_decode(lengths, (int)blockIdx.x >> 3, 7, b, tM)) return;  // 128-row tiles
    const int nq = blockIdx.x & 7;
    const int M_ = b * 16 + tM;
    const int m0 = M_ * 128;

    const int tid = threadIdx.x;
    const int wave = tid >> 6, lane = tid & 63;
    const int wr = wave >> 1, wc = wave & 1;
    const int l15 = lane & 15, quad = lane >> 4;

    const float INF = __builtin_inff();
    float minv[4][4], posv[4][4];
    int tch[4][4];
#pragma unroll
    for (int mi = 0; mi < 4; mi++)
#pragma unroll
        for (int r = 0; r < 4; r++) {
            minv[mi][r] = INF;
            posv[mi][r] = INF;
            tch[mi][r] = teacher[m0 + wr * 64 + mi * 16 + quad * 4 + r];
        }

    const int ldsoff = wave * 4096;
    const char* gA0 = (const char*)Zq + (size_t)M_ * 4 * 16384 + ldsoff + lane * 16;
    const char* gB0 = (const char*)Cq + (size_t)nq * 16 * 16384 + ldsoff + lane * 16;

    // prologue: stage tile u=0 into buffer 0
#pragma unroll
    for (int i = 0; i < 4; i++) {
        async_copy16(gA0 + i * 1024, (char*)As[0] + ldsoff + i * 1024);
        async_copy16(gB0 + i * 1024, (char*)Bs[0] + ldsoff + i * 1024);
    }
    __syncthreads();

    f32x4 acc[4][4];
    int cur = 0;
#pragma unroll 2
    for (int u = 0; u < 16; ++u) {
        const int nt = u >> 2, kt = u & 3;
        if (kt == 0) {
#pragma unroll
            for (int mi = 0; mi < 4; mi++)
#pragma unroll
                for (int ni = 0; ni < 4; ni++)
                    acc[mi][ni] = (f32x4){0.f, 0.f, 0.f, 0.f};
        }
        // issue next tile's loads BEFORE computing on the current one
        if (u < 15) {
            const int un = u + 1;
            const char* gA = gA0 + (size_t)(un & 3) * 16384;
            const char* gB = gB0 + (size_t)un * 16384;
            char* dA = (char*)As[cur ^ 1] + ldsoff;
            char* dB = (char*)Bs[cur ^ 1] + ldsoff;
#pragma unroll
            for (int i = 0; i < 4; i++) {
                async_copy16(gA + i * 1024, dA + i * 1024);
                async_copy16(gB + i * 1024, dB + i * 1024);
            }
        }

        const unsigned char* sA = As[cur];
        const unsigned char* sB = Bs[cur];
        v8i av[4], bv[4];
#pragma unroll
        for (int mi = 0; mi < 4; mi++) {
            int rg = wr * 4 + mi;
            union { uint4 q[2]; v8i v; } uu;
            uu.q[0] = *(const uint4*)(sA + rg * 2048 + lane * 16);
            uu.q[1] = *(const uint4*)(sA + rg * 2048 + 1024 + lane * 16);
            av[mi] = uu.v;
        }
#pragma unroll
        for (int ni = 0; ni < 4; ni++) {
            int rg = wc * 4 + ni;
            union { uint4 q[2]; v8i v; } uu;
            uu.q[0] = *(const uint4*)(sB + rg * 2048 + lane * 16);
            uu.q[1] = *(const uint4*)(sB + rg * 2048 + 1024 + lane * 16);
            bv[ni] = uu.v;
        }
#pragma unroll
        for (int mi = 0; mi < 4; mi++)
#pragma unroll
            for (int ni = 0; ni < 4; ni++)
                acc[mi][ni] = __builtin_amdgcn_mfma_scale_f32_16x16x128_f8f6f4(
                    av[mi], bv[ni], acc[mi][ni], 0, 0,
                    0, 0x7F7F7F7F, 0, 0x7F7F7F7F);  // scales = 1.0 (e8m0 127)

        if (kt == 3) {
            // fold: running fp32 min of (cnorm - 2*dot); teacher value captured separately
            const int n0 = (nq * 4 + nt) * 128;
            float cn[4]; int col[4];
#pragma unroll
            for (int ni = 0; ni < 4; ni++) {
                col[ni] = n0 + wc * 64 + ni * 16 + l15;
                cn[ni] = cnorm[col[ni]];
            }
#pragma unroll
            for (int mi = 0; mi < 4; mi++)
#pragma unroll
                for (int r = 0; r < 4; r++) {
                    int t = tch[mi][r];
#pragma unroll
                    for (int ni = 0; ni < 4; ni++) {
                        float val = fmaf(-2.0f, acc[mi][ni][r], cn[ni]);
                        bool ist = (col[ni] == t);
                        minv[mi][r] = fminf(minv[mi][r], ist ? INF : val);
                        posv[mi][r] = fminf(posv[mi][r], ist ? val : INF);
                    }
                }
        }
        __syncthreads();  // vmcnt(0): prefetch landed; barrier: buf[cur] free to overwrite
        cur ^= 1;
    }

    const int slot = nq * 2 + wc;  // 0..15
#pragma unroll
    for (int mi = 0; mi < 4; mi++)
#pragma unroll
        for (int r = 0; r < 4; r++) {
            float mn = minv[mi][r], ps = posv[mi][r];
#pragma unroll
            for (int off = 1; off < 16; off <<= 1) {
                mn = fminf(mn, __shfl_xor(mn, off));
                ps = fminf(ps, __shfl_xor(ps, off));
            }
            if (l15 == 0) {
                int m = m0 + wr * 64 + mi * 16 + quad * 4 + r;
                negq[(size_t)slot * NM + m] = mn;
                posq[(size_t)slot * NM + m] = ps;
            }
        }
}

// ---- kernel 3: per-row reduce over 16 slots + ticketed finalize (64 blocks only) ----
__global__ void reduce_final(const float* __restrict__ negq, const float* __restrict__ posq,
                             const float* __restrict__ npart, const int* __restrict__ lengths,
                             float* __restrict__ accum, unsigned int* __restrict__ ticket,
                             float* __restrict__ out) {
    const float INF = __builtin_inff();
    const int m = blockIdx.x * 256 + threadIdx.x;
    float mn = INF, ps = INF;
#pragma unroll
    for (int s = 0; s < 16; s++) {
        mn = fminf(mn, negq[(size_t)s * NM + m]);  // coalesced
        ps = fminf(ps, posq[(size_t)s * NM + m]);
    }
    float zn = npart[m] + npart[NM + m] + npart[2 * NM + m] + npart[3 * NM + m];
    float negd = sqrtf(fmaxf(zn + mn, 1e-12f));
    float posd = sqrtf(fmaxf(zn + ps, 1e-12f));
    float tri = fmaxf(posd - negd + MARGIN_F, 0.0f);
    int b = m >> 11;
    int tt = m & (NT - 1);
    int flen = lengths[b] / ENC_STRIDE;
    float val = (tt < flen) ? tri : 0.0f;  // select (not multiply): NaN/garbage-safe

    __shared__ float red[4];
#pragma unroll
    for (int off = 1; off < 64; off <<= 1) val += __shfl_xor(val, off);
    int lane = threadIdx.x & 63, w = threadIdx.x >> 6;
    if (lane == 0) red[w] = val;
    __syncthreads();
    if (threadIdx.x == 0) {
        atomicAdd(accum, red[0] + red[1] + red[2] + red[3]);
        __threadfence();
        unsigned int old = atomicAdd(ticket, 1u);
        if (old == 63u) {  // last block: all adds are visible
            float total = atomicAdd(accum, 0.0f);
            float cnt = 0.0f;
            for (int bb = 0; bb < NB; bb++) cnt += (float)(lengths[bb] / ENC_STRIDE);
            out[0] = total / (cnt + 1e-8f);
        }
    }
}

extern "C" void kernel_launch(void* const* d_in, const int* in_sizes, int n_in,
                              void* d_out, int out_size, void* d_ws, size_t ws_size,
                              hipStream_t stream) {
    const float* sf = (const float*)d_in[0];
    const int* teacher = (const int*)d_in[1];
    const float* cb = (const float*)d_in[2];
    const int* lengths = (const int*)d_in[3];

    char* ws = (char*)d_ws;
    unsigned char* Zq = (unsigned char*)(ws);                  //  8,388,608 B
    unsigned char* Cq = (unsigned char*)(ws + 8388608);        //  2,097,152 B
    float* cnorm = (float*)(ws + 10485760);                    //     16,384 B
    float* npart = (float*)(ws + 10502144);                    //    262,144 B (4 x NM)
    float* negq = (float*)(ws + 10764288);                     //  1,048,576 B (16 x NM)
    float* posq = (float*)(ws + 11812864);                     //  1,048,576 B
    float* accum = (float*)(ws + 12861440);                    //          4 B
    unsigned int* ticket = (unsigned int*)(ws + 12861444);     //          4 B

    prep_fused<<<1280, 256, 0, stream>>>(sf, cb, lengths, Zq, npart, Cq, cnorm, accum, ticket);
    triplet_main<<<1024, 256, 0, stream>>>(Zq, Cq, cnorm, teacher, lengths, negq, posq);
    reduce_final<<<64, 256, 0, stream>>>(negq, posq, npart, lengths, accum, ticket,
                                         (float*)d_out);
}